// Round 4
// baseline (2129.931 us; speedup 1.0000x reference)
//
#include <hip/hip_runtime.h>
#include <math.h>

// TransformersLSTM: T=512, I=512, H=1024, L=512, O=1.
// Split-grid persistent kernel: blocks 0..127 encoder, 128..255 decoder.
// R16 = R12 structure + COUNTED-EPOCH FLAG HANDOFF (poll population 65536->256).
// Evidence chain: R13 never removed the decoder's continuous 32K-thread data
// spin; R14 showed each ring alone costs ~3us/step with that spin present;
// R15 exonerated the store path. Surviving theory: LLC hot-line queueing from
// ~64K concurrent poll loads inflates discovery to ~2.6us. Fix:
//  - producers: data stores (sc0sc1) -> s_waitcnt vmcnt(0) -> atomic_add to a
//    sharded step counter (4 shards x 32 producers, one line each).
//  - consumers: ONE thread per block polls the 4 shard counters; block barrier;
//    then a single one-shot dwordx4 gather per thread.
//  - poison protocol unchanged as correctness backbone: one-shot sees poison
//    -> poll2 fallback; flag timeout -> sticky fallback to old path. Flags are
//    a perf hint only; soundness identical to R12.
//  - decoder eh keeps spec samples (lag regime = zero polls); block-uniform
//    __syncthreads_and gates the miss path onto the flag wait.
//  - flags live in workspace, zeroed via hipMemsetAsync each launch.

#define T_STEPS 512
#define ENC_BLK 128
#define NBLK    256
#define NTHR    512
#define POLL_LIMIT 30000u
#define FLAG_LIMIT 20000u

typedef float fv4 __attribute__((ext_vector_type(4)));

__device__ __forceinline__ float sigf(float x) { return 1.0f / (1.0f + expf(-x)); }

// relaxed agent-scope load: device-coherent dword load, compiler-scheduled.
__device__ __forceinline__ float ld_f(const float* p) {
  return __hip_atomic_load(p, __ATOMIC_RELAXED, __HIP_MEMORY_SCOPE_AGENT);
}

// 4B cache-bypass store (to LLC); issued by one wave, fully coalesced.
__device__ __forceinline__ void st_bypass4(float* p, float v) {
  asm volatile("global_store_dword %0, %1, off sc0 sc1"
               :: "v"(p), "v"(v) : "memory");
}

__device__ __forceinline__ bool valid4(fv4 v) {
  return __float_as_uint(v.x) != 0xAAAAAAAAu && __float_as_uint(v.y) != 0xAAAAAAAAu &&
         __float_as_uint(v.z) != 0xAAAAAAAAu && __float_as_uint(v.w) != 0xAAAAAAAAu;
}
__device__ __forceinline__ bool validf(float a, float b, float c, float d) {
  return __float_as_uint(a) != 0xAAAAAAAAu && __float_as_uint(b) != 0xAAAAAAAAu &&
         __float_as_uint(c) != 0xAAAAAAAAu && __float_as_uint(d) != 0xAAAAAAAAu;
}

// 2-deep pipelined poison-poll of one 16B granule (sliding vmcnt(1) window).
// Self-contained asm (all waits internal) -- sound. Fallback path only.
__device__ __forceinline__ fv4 poll2(const float* p, int* okp) {
  fv4 a, b;
  int ok = 1;
  asm volatile("global_load_dwordx4 %0, %1, off sc0 sc1" : "=v"(a) : "v"(p) : "memory");
  for (unsigned it = 0;; ++it) {
    asm volatile("global_load_dwordx4 %0, %1, off sc0 sc1" : "=v"(b) : "v"(p) : "memory");
    asm volatile("s_waitcnt vmcnt(1)" : "+v"(a) :: "memory");  // oldest (a) done
    if (valid4(a)) { asm volatile("s_waitcnt vmcnt(0)" ::: "memory"); break; }
    asm volatile("global_load_dwordx4 %0, %1, off sc0 sc1" : "=v"(a) : "v"(p) : "memory");
    asm volatile("s_waitcnt vmcnt(1)" : "+v"(b) :: "memory");  // oldest (b) done
    if (valid4(b)) { asm volatile("s_waitcnt vmcnt(0)" ::: "memory"); a = b; break; }
    if (it > POLL_LIMIT) { ok = 0; asm volatile("s_waitcnt vmcnt(0)" ::: "memory"); break; }
  }
  *okp = ok;
  return a;
}

// one-shot 16B device-coherent load (no spin).
__device__ __forceinline__ fv4 ld_once4(const float* p) {
  fv4 a;
  asm volatile("global_load_dwordx4 %0, %1, off sc0 sc1" : "=v"(a) : "v"(p) : "memory");
  asm volatile("s_waitcnt vmcnt(0)" : "+v"(a) :: "memory");
  return a;
}

// producer: ensure prior data stores are globally visible, then bump shard.
__device__ __forceinline__ void flag_bump(unsigned* f) {
  asm volatile("s_waitcnt vmcnt(0)" ::: "memory");
  __hip_atomic_fetch_add(f, 1u, __ATOMIC_RELAXED, __HIP_MEMORY_SCOPE_AGENT);
}

// consumer (one thread per block): wait until all 4 shards reach tgt.
// returns 0 on timeout (caller falls back to data-poison polling forever).
__device__ __forceinline__ int flag_wait(const unsigned* f, unsigned tgt) {
  for (unsigned it = 0;; ++it) {
    const unsigned a = __hip_atomic_load(f +  0, __ATOMIC_RELAXED, __HIP_MEMORY_SCOPE_AGENT);
    const unsigned b = __hip_atomic_load(f + 32, __ATOMIC_RELAXED, __HIP_MEMORY_SCOPE_AGENT);
    const unsigned c = __hip_atomic_load(f + 64, __ATOMIC_RELAXED, __HIP_MEMORY_SCOPE_AGENT);
    const unsigned d = __hip_atomic_load(f + 96, __ATOMIC_RELAXED, __HIP_MEMORY_SCOPE_AGENT);
    if (a >= tgt && b >= tgt && c >= tgt && d >= tgt) return 1;
    if (it > FLAG_LIMIT) return 0;
  }
}

// ------------- precompute PX = W_ih_e @ x_t + b_ih_e + b_hh_e -----------------
// px[(t*1024 + h)*4 + g] for gate row r = g*1024 + h.
__global__ __launch_bounds__(256) void prep_gemm(const float* __restrict__ X,
                                                 const float* __restrict__ Wih,
                                                 const float* __restrict__ bih,
                                                 const float* __restrict__ bhh,
                                                 float* __restrict__ px) {
  __shared__ float Ws[64][68];
  __shared__ float Xs[64][68];
  const int r0 = blockIdx.x * 64;
  const int t0 = blockIdx.y * 64;
  const int tid = threadIdx.x;
  const int tr = tid & 15;
  const int tc = tid >> 4;
  float acc[4][4] = {{0.f}};
  for (int k0 = 0; k0 < 512; k0 += 64) {
    __syncthreads();
    const int lr = tid >> 4;
    const int lc = (tid & 15) * 4;
#pragma unroll
    for (int rep = 0; rep < 4; rep++) {
      const int row = lr + rep * 16;
      const float4 wv = *(const float4*)&Wih[(size_t)(r0 + row) * 512 + k0 + lc];
      Ws[lc + 0][row] = wv.x; Ws[lc + 1][row] = wv.y;
      Ws[lc + 2][row] = wv.z; Ws[lc + 3][row] = wv.w;
      const float4 xv = *(const float4*)&X[(size_t)(t0 + row) * 512 + k0 + lc];
      Xs[row][lc + 0] = xv.x; Xs[row][lc + 1] = xv.y;
      Xs[row][lc + 2] = xv.z; Xs[row][lc + 3] = xv.w;
    }
    __syncthreads();
    for (int kk = 0; kk < 64; kk++) {
      float a[4], x[4];
#pragma unroll
      for (int i = 0; i < 4; i++) a[i] = Ws[kk][tr * 4 + i];
#pragma unroll
      for (int j = 0; j < 4; j++) x[j] = Xs[tc * 4 + j][kk];
#pragma unroll
      for (int i = 0; i < 4; i++)
#pragma unroll
        for (int j = 0; j < 4; j++) acc[i][j] += a[i] * x[j];
    }
  }
#pragma unroll
  for (int i = 0; i < 4; i++) {
    const int r = r0 + tr * 4 + i;
    const int g = r >> 10, h = r & 1023;
    const float bsum = bih[r] + bhh[r];
#pragma unroll
    for (int j = 0; j < 4; j++) {
      const int t = t0 + tc * 4 + j;
      px[((size_t)t * 1024 + h) * 4 + g] = acc[i][j] + bsum;
    }
  }
}

// ------------------------------ persistent kernel -----------------------------
// 512 threads: wave w (0..7) owns gate g=w>>1, h-rows j=(w&1)*4+ri (ri=lane&3);
// lane s16=lane>>2 covers K in [s16*64, s16*64+64) as 16 float4 (rot by s16).
__global__ __launch_bounds__(512, 1) void lstm_persist(
    const float* __restrict__ Whhe, const float* __restrict__ Wattn,
    const float* __restrict__ battn, const float* __restrict__ Wihd,
    const float* __restrict__ Whhd, const float* __restrict__ bihd,
    const float* __restrict__ bhhd, const float* __restrict__ Wout,
    const float* __restrict__ bout, const float* __restrict__ px,
    float* ehbuf, float* dhbuf, unsigned* flags, float* out) {
  __shared__ float4 xbuf[256];   // eh copy (both groups)
  __shared__ float4 dbuf[256];   // dh copy (decoder)
  __shared__ float  aw[512];     // softmax state (decoder)
  __shared__ float  GA[32];      // gate sums (enc ge / dec g1)
  __shared__ float  GB[32];      // dec g2
  __shared__ float  bd[32];      // decoder bias
  __shared__ float  redE[4];     // energy (eh part)
  __shared__ float  redE2[4];    // energy (dh part)
  __shared__ float  red[8];      // softmax sums (8 waves)
  __shared__ float  red2[4];     // out-dot reduce
  __shared__ int    sbad;

  unsigned* flagsE = flags;        // 4 shards x 128B apart (encoder ring)
  unsigned* flagsD = flags + 128;  // 4 shards x 128B apart (decoder ring)

  const int b    = blockIdx.x;
  const int tid  = threadIdx.x;
  const int w    = tid >> 6;
  const int lane = tid & 63;
  const int ri   = lane & 3;    // row-in-wave
  const int s16  = lane >> 2;   // K-segment 0..15 (64 floats)
  const int g    = w >> 1;      // gate index
  const int j    = ((w & 1) << 2) + ri;  // h-row within block's 8

  if (b < ENC_BLK) {
    // =========================== encoder group ===============================
    const int e = b;
    const int r = (g << 10) + (e << 3) + j;  // owned gate row
    float4 we[16];
#pragma unroll
    for (int k = 0; k < 16; k++) {
      const int m = (k + s16) & 15;
      we[k] = *(const float4*)&Whhe[(size_t)r * 1024 + s16 * 64 + m * 4];
    }
    if (tid < 256) xbuf[tid] = make_float4(0.f, 0.f, 0.f, 0.f);
    if (tid == 0) sbad = 0;
    float ec = 0.f;       // cell state (tid<8)
    int fE_alive = 1;     // meaningful in tid0 only (sticky flag-path health)
    __syncthreads();

    for (int t = 0; t < T_STEPS; t++) {
      float ge = 0.f;
#pragma unroll
      for (int k = 0; k < 16; k++) {
        const int m = (k + s16) & 15;
        const float4 x = xbuf[s16 * 16 + m];
        ge += we[k].x * x.x + we[k].y * x.y + we[k].z * x.z + we[k].w * x.w;
      }
      if (s16 == 0) ge += px[((size_t)t * 1024 + (e << 3) + j) * 4 + g];
      ge += __shfl_xor(ge, 4, 64);
      ge += __shfl_xor(ge, 8, 64);
      ge += __shfl_xor(ge, 16, 64);
      ge += __shfl_xor(ge, 32, 64);
      if (lane < 4) GA[w * 4 + lane] = ge;  // GA[g*8+j]
      __syncthreads();  // S1
      if (tid < 8) {
        const float gi = GA[tid], gf = GA[8 + tid], gg = GA[16 + tid], go = GA[24 + tid];
        const float c = sigf(gf) * ec + sigf(gi) * tanhf(gg);
        ec = c;
        const float h = sigf(go) * tanhf(c);
        st_bypass4(&ehbuf[(size_t)t * 1024 + (e << 3) + tid], h);  // coalesced 32B
      }
      // publish: data visible, then bump this block's shard counter.
      if (tid == 0) {
        flag_bump(&flagsE[(e & 3) * 32]);
        if (fE_alive) fE_alive = flag_wait(flagsE, 32u * (t + 1));
      }
      __syncthreads();  // Sf: frontier complete (or flag path dead)
      int ok = 1;
      if (tid < 256) {
        fv4 ev = ld_once4(&ehbuf[(size_t)t * 1024 + tid * 4]);
        if (!valid4(ev)) ev = poll2(&ehbuf[(size_t)t * 1024 + tid * 4], &ok);
        xbuf[tid] = make_float4(ev.x, ev.y, ev.z, ev.w);
      }
      if (!ok) sbad = 1;
      __syncthreads();  // S2
      if (sbad) break;
    }
  } else {
    // =========================== decoder group ===============================
    const int d = b - ENC_BLK;
    const int r = (g << 10) + (d << 3) + j;  // owned gate row
    float4 w1[16], wr[16];
#pragma unroll
    for (int k = 0; k < 16; k++) {
      const int m = (k + s16) & 15;
      w1[k] = *(const float4*)&Wihd[(size_t)r * 2048 + s16 * 64 + m * 4];
      const float4 a = *(const float4*)&Wihd[(size_t)r * 2048 + 1024 + s16 * 64 + m * 4];
      const float4 c = *(const float4*)&Whhd[(size_t)r * 1024 + s16 * 64 + m * 4];
      wr[k] = make_float4(a.x + c.x, a.y + c.y, a.z + c.z, a.w + c.w);
    }
    if (tid < 32) {
      const int gg2 = tid >> 3, jj2 = tid & 7;
      bd[tid] = bihd[(gg2 << 10) + (d << 3) + jj2] + bhhd[(gg2 << 10) + (d << 3) + jj2];
    }
    aw[tid] = 0.f;
    if (tid < 256) {
      xbuf[tid] = make_float4(0.f, 0.f, 0.f, 0.f);
      dbuf[tid] = make_float4(0.f, 0.f, 0.f, 0.f);
    }
    if (tid == 0) sbad = 0;
    float dc = 0.f;  // cell state (tid<8)
    int fE_alive = 1, fD_alive = 1;  // tid0-local sticky health bits
    float4 wo = make_float4(0.f, 0.f, 0.f, 0.f);
    if (tid < 256) wo = *(const float4*)&Wout[tid * 4];
    const float boutv = bout[0];
    __syncthreads();

    // loop-carried eh(t) speculative sample (compiler-managed in-flight).
    float es0 = 0.f, es1 = 0.f, es2 = 0.f, es3 = 0.f;
    if (tid < 256) {
      const float* pe = &ehbuf[(size_t)tid * 4];
      es0 = ld_f(pe + 0); es1 = ld_f(pe + 1); es2 = ld_f(pe + 2); es3 = ld_f(pe + 3);
    }

    bool failed = false;
    for (int t = 0; t < T_STEPS; t++) {
      // --- softmax partials over stale aw (overlaps in-flight eh samples) ---
      const float battn_t = battn[t];
      const float ex0 = expf(aw[tid]);  // aw in [0,1]: exp safe, no max needed
      float so = (tid == t) ? 0.f : ex0;
#pragma unroll
      for (int mk = 1; mk <= 32; mk <<= 1) so += __shfl_xor(so, mk, 64);
      if (lane == 0) red[w] = so;

      // --- consume eh(t): spec samples; block-uniform miss path is flag-gated
      // (one poller + one-shot gather), never a 32K-thread storm ---
      float4 wae = make_float4(0.f, 0.f, 0.f, 0.f);
      float4 wad = make_float4(0.f, 0.f, 0.f, 0.f);
      int myok = 1;
      if (tid < 256) {
        wae = *(const float4*)&Wattn[(size_t)t * 2048 + tid * 4];
        wad = *(const float4*)&Wattn[(size_t)t * 2048 + 1024 + tid * 4];
        myok = validf(es0, es1, es2, es3);
      }
      const int allok = __syncthreads_and(myok);
      if (!allok) {
        if (tid == 0 && fE_alive) fE_alive = flag_wait(flagsE, 32u * (t + 1));
        __syncthreads();  // block-uniform: allok is uniform
      }
      float epe = 0.f;
      int ok1 = 1;
      if (tid < 256) {
        fv4 ev;
        if (allok) {
          ev.x = es0; ev.y = es1; ev.z = es2; ev.w = es3;
        } else {
          ev = ld_once4(&ehbuf[(size_t)t * 1024 + tid * 4]);
          if (!valid4(ev)) ev = poll2(&ehbuf[(size_t)t * 1024 + tid * 4], &ok1);
        }
        epe = wae.x * ev.x + wae.y * ev.y + wae.z * ev.z + wae.w * ev.w;
        xbuf[tid] = make_float4(ev.x, ev.y, ev.z, ev.w);
      }
      if (!ok1) sbad = 1;
#pragma unroll
      for (int mk = 1; mk <= 32; mk <<= 1) epe += __shfl_xor(epe, mk, 64);
      if (lane == 0 && w < 4) redE[w] = epe;
      __syncthreads();  // B1
      if (sbad) { failed = true; break; }

      // --- issue dh(t-1) speculative samples; g1 matvec covers the RTT ---
      float ds0 = 0.f, ds1 = 0.f, ds2 = 0.f, ds3 = 0.f;
      if (t > 0 && tid < 256) {
        const float* pd = &dhbuf[(size_t)(t - 1) * 1024 + tid * 4];
        ds0 = ld_f(pd + 0); ds1 = ld_f(pd + 1); ds2 = ld_f(pd + 2); ds3 = ld_f(pd + 3);
      }

      float g1 = 0.f;
#pragma unroll
      for (int k = 0; k < 16; k++) {
        const int m = (k + s16) & 15;
        const float4 x = xbuf[s16 * 16 + m];
        g1 += w1[k].x * x.x + w1[k].y * x.y + w1[k].z * x.z + w1[k].w * x.w;
      }
      g1 += __shfl_xor(g1, 4, 64);
      g1 += __shfl_xor(g1, 8, 64);
      g1 += __shfl_xor(g1, 16, 64);
      g1 += __shfl_xor(g1, 32, 64);
      if (lane < 4) GA[w * 4 + lane] = g1;

      // --- dh(t-1) readiness: one poller on the shard counters ---
      if (t > 0 && tid == 0 && fD_alive) fD_alive = flag_wait(flagsD, 32u * t);
      __syncthreads();  // Bd: dh frontier complete (or flag path dead)

      // --- consume dh(t-1): spec-hit or one-shot; poll2 only as backstop ---
      float epd = 0.f;
      int ok2 = 1;
      if (t > 0 && tid < 256) {
        fv4 dv;
        if (validf(ds0, ds1, ds2, ds3)) {
          dv.x = ds0; dv.y = ds1; dv.z = ds2; dv.w = ds3;
        } else {
          dv = ld_once4(&dhbuf[(size_t)(t - 1) * 1024 + tid * 4]);
          if (!valid4(dv)) dv = poll2(&dhbuf[(size_t)(t - 1) * 1024 + tid * 4], &ok2);
        }
        epd = wad.x * dv.x + wad.y * dv.y + wad.z * dv.z + wad.w * dv.w;
        dbuf[tid] = make_float4(dv.x, dv.y, dv.z, dv.w);
      }
      if (!ok2) sbad = 1;
#pragma unroll
      for (int mk = 1; mk <= 32; mk <<= 1) epd += __shfl_xor(epd, mk, 64);
      if (lane == 0 && w < 4) redE2[w] = epd;
      __syncthreads();  // B2
      if (sbad) { failed = true; break; }

      // --- g2 = (Wihd[:,H:]+Whhd) @ dh(t-1) ---
      float g2 = 0.f;
#pragma unroll
      for (int k = 0; k < 16; k++) {
        const int m = (k + s16) & 15;
        const float4 dd = dbuf[s16 * 16 + m];
        g2 += wr[k].x * dd.x + wr[k].y * dd.y + wr[k].z * dd.z + wr[k].w * dd.w;
      }
      g2 += __shfl_xor(g2, 4, 64);
      g2 += __shfl_xor(g2, 8, 64);
      g2 += __shfl_xor(g2, 16, 64);
      g2 += __shfl_xor(g2, 32, 64);
      if (lane < 4) GB[w * 4 + lane] = g2;

      // --- softmax finish (all threads redundantly) + aw update ---
      const float e_t = redE[0] + redE[1] + redE[2] + redE[3] +
                        redE2[0] + redE2[1] + redE2[2] + redE2[3] + battn_t;
      const float exden = expf(e_t);
      const float inv = 1.f / (red[0] + red[1] + red[2] + red[3] +
                               red[4] + red[5] + red[6] + red[7] + exden);
      const float awt = exden * inv;
      aw[tid] = ((tid == t) ? exden : ex0) * inv;
      __syncthreads();  // S3 (GA/GB ready)

      // --- decoder cell (tid<8) + coalesced publication + shard bump ---
      if (tid < 8) {
        const float gi = awt * GA[tid]      + GB[tid]      + bd[tid];
        const float gf = awt * GA[8 + tid]  + GB[8 + tid]  + bd[8 + tid];
        const float gg = awt * GA[16 + tid] + GB[16 + tid] + bd[16 + tid];
        const float go = awt * GA[24 + tid] + GB[24 + tid] + bd[24 + tid];
        const float c = sigf(gf) * dc + sigf(gi) * tanhf(gg);
        dc = c;
        const float h = sigf(go) * tanhf(c);
        st_bypass4(&dhbuf[(size_t)t * 1024 + (d << 3) + tid], h);
      }
      if (tid == 0) flag_bump(&flagsD[(d & 3) * 32]);

      // --- issue eh(t+1) speculative samples (in flight across back edge) ---
      if (tid < 256) {
        const int tn = (t + 1 < T_STEPS) ? (t + 1) : t;  // last iter: harmless
        const float* pe = &ehbuf[(size_t)tn * 1024 + tid * 4];
        es0 = ld_f(pe + 0); es1 = ld_f(pe + 1); es2 = ld_f(pe + 2); es3 = ld_f(pe + 3);
      }
    }

    // --- epilogue: out[t] = W_out·dh(t) + b_out, 4 t-values per block ---
    if (!failed) {
#pragma unroll
      for (int i = 0; i < 4; i++) {
        const int t = d * 4 + i;
        float op = 0.f;
        int ok = 1;
        if (tid < 256) {
          const fv4 dv = poll2(&dhbuf[(size_t)t * 1024 + tid * 4], &ok);
          op = wo.x * dv.x + wo.y * dv.y + wo.z * dv.z + wo.w * dv.w;
        }
        if (!ok) break;
#pragma unroll
        for (int mk = 1; mk <= 32; mk <<= 1) op += __shfl_xor(op, mk, 64);
        if (lane == 0 && w < 4) red2[w] = op;
        __syncthreads();
        if (tid == 0) out[t] = red2[0] + red2[1] + red2[2] + red2[3] + boutv;
        __syncthreads();
      }
    }
  }
}

// ---------------------------------- launch ------------------------------------
extern "C" void kernel_launch(void* const* d_in, const int* in_sizes, int n_in,
                              void* d_out, int out_size, void* d_ws, size_t ws_size,
                              hipStream_t stream) {
  const float* X     = (const float*)d_in[0];
  const float* Wihe  = (const float*)d_in[2];
  const float* Whhe  = (const float*)d_in[3];
  const float* bihe  = (const float*)d_in[4];
  const float* bhhe  = (const float*)d_in[5];
  const float* Wattn = (const float*)d_in[6];
  const float* battn = (const float*)d_in[7];
  const float* Wihd  = (const float*)d_in[8];
  const float* Whhd  = (const float*)d_in[9];
  const float* bihd  = (const float*)d_in[10];
  const float* bhhd  = (const float*)d_in[11];
  const float* Wo    = (const float*)d_in[12];
  const float* bo    = (const float*)d_in[13];
  float* out = (float*)d_out;

  float* ws    = (float*)d_ws;
  float* px    = ws;                                  // 512*1024*4 floats (8 MB)
  float* ehbuf = px + (size_t)T_STEPS * 1024 * 4;     // 512*1024 (2 MB)
  float* dhbuf = ehbuf + (size_t)T_STEPS * 1024;      // 512*1024 (2 MB)
  unsigned* flags = (unsigned*)(dhbuf + (size_t)T_STEPS * 1024);  // 256 uints
  const size_t need = ((size_t)T_STEPS * 1024 * 6) * sizeof(float) + 1024;
  if (ws_size < need) return;

  hipMemsetAsync(flags, 0, 1024, stream);  // zero epoch counters (every replay)
  prep_gemm<<<dim3(64, 8), 256, 0, stream>>>(X, Wihe, bihe, bhhe, px);
  lstm_persist<<<NBLK, NTHR, 0, stream>>>(
      Whhe, Wattn, battn, Wihd, Whhd, bihd, bhhd, Wo, bo, px, ehbuf, dhbuf,
      flags, out);
}

// Round 5
// 2069.127 us; speedup vs baseline: 1.0294x; 1.0294x over previous
//
#include <hip/hip_runtime.h>
#include <math.h>

// TransformersLSTM: T=512, I=512, H=1024, L=512, O=1.
// Split-grid persistent kernel: blocks 0..127 encoder, 128..255 decoder.
// R17 = R12 structure + CLOCK-RENDEZVOUS TIMED GATHER on both rings.
// Evidence: R14 showed the decoder chain (3.26us/step) sets the period; the
// dh-poll storm was never removed (R13 only touched the encoder side); R16
// showed flag+serial-one-shot costs MORE (each device-scope leg ~1us).
// Mechanism: s_memrealtime is chip-global constant-rate. Each block
// self-calibrates, in ticks: P (its step period, EMA) and W (wait offset from
// its own publish-anchor to the moment a one-shot gather should be ISSUED,
// aiming at visibility - L/2 so the load arrives just after the data commits).
// Gather = spin-sleep until anchor+W -> ONE speculative dwordx4 per thread ->
// poison-validate -> poll2 fallback (rare; W adapts: all-hit shrink / miss
// grow). Steady state: ~zero poll traffic, discovery ~= V_s + L/2.
// Soundness: poison-check backbone identical to R12; timing is only a hint;
// spins and polls are iteration-bounded; W/P are per-launch registers.

#define T_STEPS 512
#define ENC_BLK 128
#define NBLK    256
#define NTHR    512
#define POLL_LIMIT 30000u
#define SPIN_LIMIT 200000

typedef float fv4 __attribute__((ext_vector_type(4)));
typedef unsigned long long u64;

__device__ __forceinline__ float sigf(float x) { return 1.0f / (1.0f + expf(-x)); }

// relaxed agent-scope load: device-coherent dword load, compiler-scheduled.
__device__ __forceinline__ float ld_f(const float* p) {
  return __hip_atomic_load(p, __ATOMIC_RELAXED, __HIP_MEMORY_SCOPE_AGENT);
}

// 4B cache-bypass store (to LLC); issued by one wave, fully coalesced.
__device__ __forceinline__ void st_bypass4(float* p, float v) {
  asm volatile("global_store_dword %0, %1, off sc0 sc1"
               :: "v"(p), "v"(v) : "memory");
}

__device__ __forceinline__ bool valid4(fv4 v) {
  return __float_as_uint(v.x) != 0xAAAAAAAAu && __float_as_uint(v.y) != 0xAAAAAAAAu &&
         __float_as_uint(v.z) != 0xAAAAAAAAu && __float_as_uint(v.w) != 0xAAAAAAAAu;
}
__device__ __forceinline__ bool validf(float a, float b, float c, float d) {
  return __float_as_uint(a) != 0xAAAAAAAAu && __float_as_uint(b) != 0xAAAAAAAAu &&
         __float_as_uint(c) != 0xAAAAAAAAu && __float_as_uint(d) != 0xAAAAAAAAu;
}

// 2-deep pipelined poison-poll of one 16B granule (sliding vmcnt(1) window).
// Self-contained asm (all waits internal) -- sound. Fallback path only.
__device__ __forceinline__ fv4 poll2(const float* p, int* okp) {
  fv4 a, b;
  int ok = 1;
  asm volatile("global_load_dwordx4 %0, %1, off sc0 sc1" : "=v"(a) : "v"(p) : "memory");
  for (unsigned it = 0;; ++it) {
    asm volatile("global_load_dwordx4 %0, %1, off sc0 sc1" : "=v"(b) : "v"(p) : "memory");
    asm volatile("s_waitcnt vmcnt(1)" : "+v"(a) :: "memory");  // oldest (a) done
    if (valid4(a)) { asm volatile("s_waitcnt vmcnt(0)" ::: "memory"); break; }
    asm volatile("global_load_dwordx4 %0, %1, off sc0 sc1" : "=v"(a) : "v"(p) : "memory");
    asm volatile("s_waitcnt vmcnt(1)" : "+v"(b) :: "memory");  // oldest (b) done
    if (valid4(b)) { asm volatile("s_waitcnt vmcnt(0)" ::: "memory"); a = b; break; }
    if (it > POLL_LIMIT) { ok = 0; asm volatile("s_waitcnt vmcnt(0)" ::: "memory"); break; }
  }
  *okp = ok;
  return a;
}

// one-shot 16B device-coherent load (no spin).
__device__ __forceinline__ fv4 ld_once4(const float* p) {
  fv4 a;
  asm volatile("global_load_dwordx4 %0, %1, off sc0 sc1" : "=v"(a) : "v"(p) : "memory");
  asm volatile("s_waitcnt vmcnt(0)" : "+v"(a) :: "memory");
  return a;
}

// bounded spin-sleep until chip-global realtime tick tgt.
__device__ __forceinline__ void spin_until(u64 tgt) {
  int g = 0;
  while (__builtin_amdgcn_s_memrealtime() < tgt && ++g < SPIN_LIMIT)
    __builtin_amdgcn_s_sleep(1);
}

// ------------- precompute PX = W_ih_e @ x_t + b_ih_e + b_hh_e -----------------
// px[(t*1024 + h)*4 + g] for gate row r = g*1024 + h.
__global__ __launch_bounds__(256) void prep_gemm(const float* __restrict__ X,
                                                 const float* __restrict__ Wih,
                                                 const float* __restrict__ bih,
                                                 const float* __restrict__ bhh,
                                                 float* __restrict__ px) {
  __shared__ float Ws[64][68];
  __shared__ float Xs[64][68];
  const int r0 = blockIdx.x * 64;
  const int t0 = blockIdx.y * 64;
  const int tid = threadIdx.x;
  const int tr = tid & 15;
  const int tc = tid >> 4;
  float acc[4][4] = {{0.f}};
  for (int k0 = 0; k0 < 512; k0 += 64) {
    __syncthreads();
    const int lr = tid >> 4;
    const int lc = (tid & 15) * 4;
#pragma unroll
    for (int rep = 0; rep < 4; rep++) {
      const int row = lr + rep * 16;
      const float4 wv = *(const float4*)&Wih[(size_t)(r0 + row) * 512 + k0 + lc];
      Ws[lc + 0][row] = wv.x; Ws[lc + 1][row] = wv.y;
      Ws[lc + 2][row] = wv.z; Ws[lc + 3][row] = wv.w;
      const float4 xv = *(const float4*)&X[(size_t)(t0 + row) * 512 + k0 + lc];
      Xs[row][lc + 0] = xv.x; Xs[row][lc + 1] = xv.y;
      Xs[row][lc + 2] = xv.z; Xs[row][lc + 3] = xv.w;
    }
    __syncthreads();
    for (int kk = 0; kk < 64; kk++) {
      float a[4], x[4];
#pragma unroll
      for (int i = 0; i < 4; i++) a[i] = Ws[kk][tr * 4 + i];
#pragma unroll
      for (int j = 0; j < 4; j++) x[j] = Xs[tc * 4 + j][kk];
#pragma unroll
      for (int i = 0; i < 4; i++)
#pragma unroll
        for (int j = 0; j < 4; j++) acc[i][j] += a[i] * x[j];
    }
  }
#pragma unroll
  for (int i = 0; i < 4; i++) {
    const int r = r0 + tr * 4 + i;
    const int g = r >> 10, h = r & 1023;
    const float bsum = bih[r] + bhh[r];
#pragma unroll
    for (int j = 0; j < 4; j++) {
      const int t = t0 + tc * 4 + j;
      px[((size_t)t * 1024 + h) * 4 + g] = acc[i][j] + bsum;
    }
  }
}

// ------------------------------ persistent kernel -----------------------------
// 512 threads: wave w (0..7) owns gate g=w>>1, h-rows j=(w&1)*4+ri (ri=lane&3);
// lane s16=lane>>2 covers K in [s16*64, s16*64+64) as 16 float4 (rot by s16).
__global__ __launch_bounds__(512, 1) void lstm_persist(
    const float* __restrict__ Whhe, const float* __restrict__ Wattn,
    const float* __restrict__ battn, const float* __restrict__ Wihd,
    const float* __restrict__ Whhd, const float* __restrict__ bihd,
    const float* __restrict__ bhhd, const float* __restrict__ Wout,
    const float* __restrict__ bout, const float* __restrict__ px,
    float* ehbuf, float* dhbuf, float* out) {
  __shared__ float4 xbuf[256];   // eh copy (both groups)
  __shared__ float4 dbuf[256];   // dh copy (decoder)
  __shared__ float  aw[512];     // softmax state (decoder)
  __shared__ float  GA[32];      // gate sums (enc ge / dec g1)
  __shared__ float  GB[32];      // dec g2
  __shared__ float  bd[32];      // decoder bias
  __shared__ float  redE[4];     // energy (eh part)
  __shared__ float  redE2[4];    // energy (dh part)
  __shared__ float  red[8];      // softmax sums (8 waves)
  __shared__ float  red2[4];     // out-dot reduce
  __shared__ int    sbad;

  const int b    = blockIdx.x;
  const int tid  = threadIdx.x;
  const int w    = tid >> 6;
  const int lane = tid & 63;
  const int ri   = lane & 3;    // row-in-wave
  const int s16  = lane >> 2;   // K-segment 0..15 (64 floats)
  const int g    = w >> 1;      // gate index
  const int j    = ((w & 1) << 2) + ri;  // h-row within block's 8

  if (b < ENC_BLK) {
    // =========================== encoder group ===============================
    const int e = b;
    const int r = (g << 10) + (e << 3) + j;  // owned gate row
    float4 we[16];
#pragma unroll
    for (int k = 0; k < 16; k++) {
      const int m = (k + s16) & 15;
      we[k] = *(const float4*)&Whhe[(size_t)r * 1024 + s16 * 64 + m * 4];
    }
    if (tid < 256) xbuf[tid] = make_float4(0.f, 0.f, 0.f, 0.f);
    if (tid == 0) sbad = 0;
    float ec = 0.f;  // cell state (tid<8)
    u64 rp_prev = 0, P = 0, W = 0;  // per-wave rendezvous state (self-consistent)
    __syncthreads();

    for (int t = 0; t < T_STEPS; t++) {
      float ge = 0.f;
#pragma unroll
      for (int k = 0; k < 16; k++) {
        const int m = (k + s16) & 15;
        const float4 x = xbuf[s16 * 16 + m];
        ge += we[k].x * x.x + we[k].y * x.y + we[k].z * x.z + we[k].w * x.w;
      }
      if (s16 == 0) ge += px[((size_t)t * 1024 + (e << 3) + j) * 4 + g];
      ge += __shfl_xor(ge, 4, 64);
      ge += __shfl_xor(ge, 8, 64);
      ge += __shfl_xor(ge, 16, 64);
      ge += __shfl_xor(ge, 32, 64);
      if (lane < 4) GA[w * 4 + lane] = ge;  // GA[g*8+j]
      __syncthreads();  // S1
      if (tid < 8) {
        const float gi = GA[tid], gf = GA[8 + tid], gg = GA[16 + tid], go = GA[24 + tid];
        const float c = sigf(gf) * ec + sigf(gi) * tanhf(gg);
        ec = c;
        const float h = sigf(go) * tanhf(c);
        st_bypass4(&ehbuf[(size_t)t * 1024 + (e << 3) + tid], h);  // coalesced 32B
      }
      // --- rendezvous anchor + P/W calibration (publish-time proxy) ---
      const u64 rp = __builtin_amdgcn_s_memrealtime();
      if (t >= 1) {
        u64 pm = rp - rp_prev;
        if (t == 1) P = pm;
        else { if (pm > (P << 1)) pm = P << 1; P = P - (P >> 2) + (pm >> 2); }
        if (t == 2) W = (P >> 2) + (P >> 4);  // init ~0.31*P
      }
      rp_prev = rp;
      // --- timed speculative gather; poison backbone; poll2 fallback ---
      int ok = 1, myhit = 1;
      if (tid < 256) {
        if (W) spin_until(rp + W);
        fv4 ev = ld_once4(&ehbuf[(size_t)t * 1024 + tid * 4]);
        if (!valid4(ev)) { myhit = 0; ev = poll2(&ehbuf[(size_t)t * 1024 + tid * 4], &ok); }
        xbuf[tid] = make_float4(ev.x, ev.y, ev.z, ev.w);
      }
      if (!ok) sbad = 1;
      const int allhit = __syncthreads_and(myhit);  // also the S2 barrier
      if (t >= 2) {
        if (allhit) { const u64 dn = P >> 6; W -= (W < dn ? W : dn); }
        else        { W += (P >> 5); if (W > P) W = P; }
      }
      if (sbad) break;
    }
  } else {
    // =========================== decoder group ===============================
    const int d = b - ENC_BLK;
    const int r = (g << 10) + (d << 3) + j;  // owned gate row
    float4 w1[16], wr[16];
#pragma unroll
    for (int k = 0; k < 16; k++) {
      const int m = (k + s16) & 15;
      w1[k] = *(const float4*)&Wihd[(size_t)r * 2048 + s16 * 64 + m * 4];
      const float4 a = *(const float4*)&Wihd[(size_t)r * 2048 + 1024 + s16 * 64 + m * 4];
      const float4 c = *(const float4*)&Whhd[(size_t)r * 1024 + s16 * 64 + m * 4];
      wr[k] = make_float4(a.x + c.x, a.y + c.y, a.z + c.z, a.w + c.w);
    }
    if (tid < 32) {
      const int gg2 = tid >> 3, jj2 = tid & 7;
      bd[tid] = bihd[(gg2 << 10) + (d << 3) + jj2] + bhhd[(gg2 << 10) + (d << 3) + jj2];
    }
    aw[tid] = 0.f;
    if (tid < 256) {
      xbuf[tid] = make_float4(0.f, 0.f, 0.f, 0.f);
      dbuf[tid] = make_float4(0.f, 0.f, 0.f, 0.f);
    }
    if (tid == 0) sbad = 0;
    float dc = 0.f;  // cell state (tid<8)
    u64 rpd_prev = 0, Pd = 0, Wd = 0;  // per-wave rendezvous state (dh ring)
    float4 wo = make_float4(0.f, 0.f, 0.f, 0.f);
    if (tid < 256) wo = *(const float4*)&Wout[tid * 4];
    const float boutv = bout[0];
    __syncthreads();

    // loop-carried eh(t) speculative sample (enc runs ahead -> these hit).
    float es0 = 0.f, es1 = 0.f, es2 = 0.f, es3 = 0.f;
    if (tid < 256) {
      const float* pe = &ehbuf[(size_t)tid * 4];
      es0 = ld_f(pe + 0); es1 = ld_f(pe + 1); es2 = ld_f(pe + 2); es3 = ld_f(pe + 3);
    }

    bool failed = false;
    for (int t = 0; t < T_STEPS; t++) {
      // --- softmax partials over stale aw (overlaps in-flight eh samples) ---
      const float battn_t = battn[t];
      const float ex0 = expf(aw[tid]);  // aw in [0,1]: exp safe, no max needed
      float so = (tid == t) ? 0.f : ex0;
#pragma unroll
      for (int mk = 1; mk <= 32; mk <<= 1) so += __shfl_xor(so, mk, 64);
      if (lane == 0) red[w] = so;

      // --- consume eh(t): spec samples (hit in steady state: enc is ahead) ---
      float4 wae = make_float4(0.f, 0.f, 0.f, 0.f);
      float4 wad = make_float4(0.f, 0.f, 0.f, 0.f);
      float epe = 0.f;
      int ok1 = 1;
      if (tid < 256) {
        wae = *(const float4*)&Wattn[(size_t)t * 2048 + tid * 4];
        wad = *(const float4*)&Wattn[(size_t)t * 2048 + 1024 + tid * 4];
        fv4 ev;
        if (validf(es0, es1, es2, es3)) {
          ev.x = es0; ev.y = es1; ev.z = es2; ev.w = es3;
        } else {
          ev = poll2(&ehbuf[(size_t)t * 1024 + tid * 4], &ok1);
        }
        epe = wae.x * ev.x + wae.y * ev.y + wae.z * ev.z + wae.w * ev.w;
        xbuf[tid] = make_float4(ev.x, ev.y, ev.z, ev.w);
      }
      if (!ok1) sbad = 1;
#pragma unroll
      for (int mk = 1; mk <= 32; mk <<= 1) epe += __shfl_xor(epe, mk, 64);
      if (lane == 0 && w < 4) redE[w] = epe;
      __syncthreads();  // B1
      if (sbad) { failed = true; break; }

      // --- rendezvous anchor (fixed point in loop; offset absorbed in Wd) ---
      const u64 rpd = __builtin_amdgcn_s_memrealtime();
      if (t >= 1) {
        u64 pm = rpd - rpd_prev;
        if (t == 1) Pd = pm;
        else { if (pm > (Pd << 1)) pm = Pd << 1; Pd = Pd - (Pd >> 2) + (pm >> 2); }
        if (t == 2) Wd = (Pd >> 2);  // init ~0.25*P (anchor is ~0.3us post-publish)
      }
      rpd_prev = rpd;

      // --- g1 = W1 @ eh(t): runs while dh(t-1) propagates ---
      float g1 = 0.f;
#pragma unroll
      for (int k = 0; k < 16; k++) {
        const int m = (k + s16) & 15;
        const float4 x = xbuf[s16 * 16 + m];
        g1 += w1[k].x * x.x + w1[k].y * x.y + w1[k].z * x.z + w1[k].w * x.w;
      }
      g1 += __shfl_xor(g1, 4, 64);
      g1 += __shfl_xor(g1, 8, 64);
      g1 += __shfl_xor(g1, 16, 64);
      g1 += __shfl_xor(g1, 32, 64);
      if (lane < 4) GA[w * 4 + lane] = g1;

      // --- consume dh(t-1): timed speculative gather + poison backbone ---
      float epd = 0.f;
      int ok2 = 1, myhit2 = 1;
      if (t > 0 && tid < 256) {
        if (Wd) spin_until(rpd + Wd);
        fv4 dv = ld_once4(&dhbuf[(size_t)(t - 1) * 1024 + tid * 4]);
        if (!valid4(dv)) { myhit2 = 0; dv = poll2(&dhbuf[(size_t)(t - 1) * 1024 + tid * 4], &ok2); }
        epd = wad.x * dv.x + wad.y * dv.y + wad.z * dv.z + wad.w * dv.w;
        dbuf[tid] = make_float4(dv.x, dv.y, dv.z, dv.w);
      }
      if (!ok2) sbad = 1;
#pragma unroll
      for (int mk = 1; mk <= 32; mk <<= 1) epd += __shfl_xor(epd, mk, 64);
      if (lane == 0 && w < 4) redE2[w] = epd;
      const int allhit2 = __syncthreads_and(myhit2);  // also the B2 barrier
      if (t >= 3) {
        if (allhit2) { const u64 dn = Pd >> 6; Wd -= (Wd < dn ? Wd : dn); }
        else         { Wd += (Pd >> 5); if (Wd > Pd) Wd = Pd; }
      }
      if (sbad) { failed = true; break; }

      // --- g2 = (Wihd[:,H:]+Whhd) @ dh(t-1) ---
      float g2 = 0.f;
#pragma unroll
      for (int k = 0; k < 16; k++) {
        const int m = (k + s16) & 15;
        const float4 dd = dbuf[s16 * 16 + m];
        g2 += wr[k].x * dd.x + wr[k].y * dd.y + wr[k].z * dd.z + wr[k].w * dd.w;
      }
      g2 += __shfl_xor(g2, 4, 64);
      g2 += __shfl_xor(g2, 8, 64);
      g2 += __shfl_xor(g2, 16, 64);
      g2 += __shfl_xor(g2, 32, 64);
      if (lane < 4) GB[w * 4 + lane] = g2;

      // --- softmax finish (all threads redundantly) + aw update ---
      const float e_t = redE[0] + redE[1] + redE[2] + redE[3] +
                        redE2[0] + redE2[1] + redE2[2] + redE2[3] + battn_t;
      const float exden = expf(e_t);
      const float inv = 1.f / (red[0] + red[1] + red[2] + red[3] +
                               red[4] + red[5] + red[6] + red[7] + exden);
      const float awt = exden * inv;
      aw[tid] = ((tid == t) ? exden : ex0) * inv;
      __syncthreads();  // S3 (GA/GB ready)

      // --- decoder cell (tid<8) + coalesced publication ---
      if (tid < 8) {
        const float gi = awt * GA[tid]      + GB[tid]      + bd[tid];
        const float gf = awt * GA[8 + tid]  + GB[8 + tid]  + bd[8 + tid];
        const float gg = awt * GA[16 + tid] + GB[16 + tid] + bd[16 + tid];
        const float go = awt * GA[24 + tid] + GB[24 + tid] + bd[24 + tid];
        const float c = sigf(gf) * dc + sigf(gi) * tanhf(gg);
        dc = c;
        const float h = sigf(go) * tanhf(c);
        st_bypass4(&dhbuf[(size_t)t * 1024 + (d << 3) + tid], h);
      }

      // --- issue eh(t+1) speculative samples (in flight across back edge) ---
      if (tid < 256) {
        const int tn = (t + 1 < T_STEPS) ? (t + 1) : t;  // last iter: harmless
        const float* pe = &ehbuf[(size_t)tn * 1024 + tid * 4];
        es0 = ld_f(pe + 0); es1 = ld_f(pe + 1); es2 = ld_f(pe + 2); es3 = ld_f(pe + 3);
      }
    }

    // --- epilogue: out[t] = W_out·dh(t) + b_out, 4 t-values per block ---
    if (!failed) {
#pragma unroll
      for (int i = 0; i < 4; i++) {
        const int t = d * 4 + i;
        float op = 0.f;
        int ok = 1;
        if (tid < 256) {
          const fv4 dv = poll2(&dhbuf[(size_t)t * 1024 + tid * 4], &ok);
          op = wo.x * dv.x + wo.y * dv.y + wo.z * dv.z + wo.w * dv.w;
        }
        if (!ok) break;
#pragma unroll
        for (int mk = 1; mk <= 32; mk <<= 1) op += __shfl_xor(op, mk, 64);
        if (lane == 0 && w < 4) red2[w] = op;
        __syncthreads();
        if (tid == 0) out[t] = red2[0] + red2[1] + red2[2] + red2[3] + boutv;
        __syncthreads();
      }
    }
  }
}

// ---------------------------------- launch ------------------------------------
extern "C" void kernel_launch(void* const* d_in, const int* in_sizes, int n_in,
                              void* d_out, int out_size, void* d_ws, size_t ws_size,
                              hipStream_t stream) {
  const float* X     = (const float*)d_in[0];
  const float* Wihe  = (const float*)d_in[2];
  const float* Whhe  = (const float*)d_in[3];
  const float* bihe  = (const float*)d_in[4];
  const float* bhhe  = (const float*)d_in[5];
  const float* Wattn = (const float*)d_in[6];
  const float* battn = (const float*)d_in[7];
  const float* Wihd  = (const float*)d_in[8];
  const float* Whhd  = (const float*)d_in[9];
  const float* bihd  = (const float*)d_in[10];
  const float* bhhd  = (const float*)d_in[11];
  const float* Wo    = (const float*)d_in[12];
  const float* bo    = (const float*)d_in[13];
  float* out = (float*)d_out;

  float* ws    = (float*)d_ws;
  float* px    = ws;                                  // 512*1024*4 floats (8 MB)
  float* ehbuf = px + (size_t)T_STEPS * 1024 * 4;     // 512*1024 (2 MB)
  float* dhbuf = ehbuf + (size_t)T_STEPS * 1024;      // 512*1024 (2 MB)
  const size_t need = ((size_t)T_STEPS * 1024 * 6) * sizeof(float);
  if (ws_size < need) return;

  prep_gemm<<<dim3(64, 8), 256, 0, stream>>>(X, Wihe, bihe, bhhe, px);
  lstm_persist<<<NBLK, NTHR, 0, stream>>>(
      Whhe, Wattn, battn, Wihd, Whhd, bihd, bhhd, Wo, bo, px, ehbuf, dhbuf, out);
}

// Round 6
// 2055.194 us; speedup vs baseline: 1.0364x; 1.0068x over previous
//
#include <hip/hip_runtime.h>
#include <math.h>

// TransformersLSTM: T=512, I=512, H=1024, L=512, O=1.
// Split-grid persistent kernel: blocks 0..127 encoder, 128..255 decoder.
// R18 = R12 structure + SENTINEL-GATED GATHER ON BOTH RINGS (the decisive
// write-commit-congestion test, finally applied to the DECODER ring which
// sets the system period).
// Evidence chain: R13 sentinels touched enc only (invisible: period=max=dec);
// R15 producer-side change neutral; R16 flags / R17 timers (serialized
// discovery) both LOSE to continuous polling. Period model: P = V + gap,
// observed P=3.26us, gap~0.5us => V~2.6us >> LLC RTT. Last standing theory:
// consumer read-storm on the frontier lines delays the producer's WRITE
// commit. Changes vs R12:
//  - dh spec samples DELETED (issued ~1.5us after publish, V>lead: never hit;
//    pure hot-window traffic).
//  - idle waves 6-7 (tids 384..511, idle during consume in both rings) act as
//    128 sentinels, one per producer, polling 2-deep with s_sleep(2) throttle
//    (~3-6x fewer outstanding reads/line during the commit window).
//  - after a barrier, the 256 consumers do a ONE-SHOT gather + per-granule
//    poison check + poll2 fallback. Poison backbone identical to R12 =>
//    soundness unchanged.
//  - decoder eh path keeps spec samples (enc runs ahead; they hit).

#define T_STEPS 512
#define ENC_BLK 128
#define NBLK    256
#define NTHR    512
#define POLL_LIMIT 30000u

typedef float fv4 __attribute__((ext_vector_type(4)));

__device__ __forceinline__ float sigf(float x) { return 1.0f / (1.0f + expf(-x)); }

// relaxed agent-scope load: device-coherent dword load, compiler-scheduled.
__device__ __forceinline__ float ld_f(const float* p) {
  return __hip_atomic_load(p, __ATOMIC_RELAXED, __HIP_MEMORY_SCOPE_AGENT);
}

// 4B cache-bypass store (to LLC); issued by one wave, fully coalesced.
__device__ __forceinline__ void st_bypass4(float* p, float v) {
  asm volatile("global_store_dword %0, %1, off sc0 sc1"
               :: "v"(p), "v"(v) : "memory");
}

__device__ __forceinline__ bool valid4(fv4 v) {
  return __float_as_uint(v.x) != 0xAAAAAAAAu && __float_as_uint(v.y) != 0xAAAAAAAAu &&
         __float_as_uint(v.z) != 0xAAAAAAAAu && __float_as_uint(v.w) != 0xAAAAAAAAu;
}
__device__ __forceinline__ bool validf(float a, float b, float c, float d) {
  return __float_as_uint(a) != 0xAAAAAAAAu && __float_as_uint(b) != 0xAAAAAAAAu &&
         __float_as_uint(c) != 0xAAAAAAAAu && __float_as_uint(d) != 0xAAAAAAAAu;
}

// 2-deep pipelined poison-poll of one 16B granule (sliding vmcnt(1) window).
// Self-contained asm (all waits internal) -- sound. SLP>0 adds s_sleep
// throttle per retry (sentinel mode: fewer outstanding reads on the line).
template <int SLP>
__device__ __forceinline__ fv4 poll2(const float* p, int* okp) {
  fv4 a, b;
  int ok = 1;
  asm volatile("global_load_dwordx4 %0, %1, off sc0 sc1" : "=v"(a) : "v"(p) : "memory");
  for (unsigned it = 0;; ++it) {
    asm volatile("global_load_dwordx4 %0, %1, off sc0 sc1" : "=v"(b) : "v"(p) : "memory");
    asm volatile("s_waitcnt vmcnt(1)" : "+v"(a) :: "memory");  // oldest (a) done
    if (valid4(a)) { asm volatile("s_waitcnt vmcnt(0)" ::: "memory"); break; }
    if (SLP) __builtin_amdgcn_s_sleep(SLP);
    asm volatile("global_load_dwordx4 %0, %1, off sc0 sc1" : "=v"(a) : "v"(p) : "memory");
    asm volatile("s_waitcnt vmcnt(1)" : "+v"(b) :: "memory");  // oldest (b) done
    if (valid4(b)) { asm volatile("s_waitcnt vmcnt(0)" ::: "memory"); a = b; break; }
    if (it > POLL_LIMIT) { ok = 0; asm volatile("s_waitcnt vmcnt(0)" ::: "memory"); break; }
    if (SLP) __builtin_amdgcn_s_sleep(SLP);
  }
  *okp = ok;
  return a;
}

// one-shot 16B device-coherent load (no spin).
__device__ __forceinline__ fv4 ld_once4(const float* p) {
  fv4 a;
  asm volatile("global_load_dwordx4 %0, %1, off sc0 sc1" : "=v"(a) : "v"(p) : "memory");
  asm volatile("s_waitcnt vmcnt(0)" : "+v"(a) :: "memory");
  return a;
}

// ------------- precompute PX = W_ih_e @ x_t + b_ih_e + b_hh_e -----------------
// px[(t*1024 + h)*4 + g] for gate row r = g*1024 + h.
__global__ __launch_bounds__(256) void prep_gemm(const float* __restrict__ X,
                                                 const float* __restrict__ Wih,
                                                 const float* __restrict__ bih,
                                                 const float* __restrict__ bhh,
                                                 float* __restrict__ px) {
  __shared__ float Ws[64][68];
  __shared__ float Xs[64][68];
  const int r0 = blockIdx.x * 64;
  const int t0 = blockIdx.y * 64;
  const int tid = threadIdx.x;
  const int tr = tid & 15;
  const int tc = tid >> 4;
  float acc[4][4] = {{0.f}};
  for (int k0 = 0; k0 < 512; k0 += 64) {
    __syncthreads();
    const int lr = tid >> 4;
    const int lc = (tid & 15) * 4;
#pragma unroll
    for (int rep = 0; rep < 4; rep++) {
      const int row = lr + rep * 16;
      const float4 wv = *(const float4*)&Wih[(size_t)(r0 + row) * 512 + k0 + lc];
      Ws[lc + 0][row] = wv.x; Ws[lc + 1][row] = wv.y;
      Ws[lc + 2][row] = wv.z; Ws[lc + 3][row] = wv.w;
      const float4 xv = *(const float4*)&X[(size_t)(t0 + row) * 512 + k0 + lc];
      Xs[row][lc + 0] = xv.x; Xs[row][lc + 1] = xv.y;
      Xs[row][lc + 2] = xv.z; Xs[row][lc + 3] = xv.w;
    }
    __syncthreads();
    for (int kk = 0; kk < 64; kk++) {
      float a[4], x[4];
#pragma unroll
      for (int i = 0; i < 4; i++) a[i] = Ws[kk][tr * 4 + i];
#pragma unroll
      for (int j = 0; j < 4; j++) x[j] = Xs[tc * 4 + j][kk];
#pragma unroll
      for (int i = 0; i < 4; i++)
#pragma unroll
        for (int j = 0; j < 4; j++) acc[i][j] += a[i] * x[j];
    }
  }
#pragma unroll
  for (int i = 0; i < 4; i++) {
    const int r = r0 + tr * 4 + i;
    const int g = r >> 10, h = r & 1023;
    const float bsum = bih[r] + bhh[r];
#pragma unroll
    for (int j = 0; j < 4; j++) {
      const int t = t0 + tc * 4 + j;
      px[((size_t)t * 1024 + h) * 4 + g] = acc[i][j] + bsum;
    }
  }
}

// ------------------------------ persistent kernel -----------------------------
// 512 threads: wave w (0..7) owns gate g=w>>1, h-rows j=(w&1)*4+ri (ri=lane&3);
// lane s16=lane>>2 covers K in [s16*64, s16*64+64) as 16 float4 (rot by s16).
__global__ __launch_bounds__(512, 1) void lstm_persist(
    const float* __restrict__ Whhe, const float* __restrict__ Wattn,
    const float* __restrict__ battn, const float* __restrict__ Wihd,
    const float* __restrict__ Whhd, const float* __restrict__ bihd,
    const float* __restrict__ bhhd, const float* __restrict__ Wout,
    const float* __restrict__ bout, const float* __restrict__ px,
    float* ehbuf, float* dhbuf, float* out) {
  __shared__ float4 xbuf[256];   // eh copy (both groups)
  __shared__ float4 dbuf[256];   // dh copy (decoder)
  __shared__ float  aw[512];     // softmax state (decoder)
  __shared__ float  GA[32];      // gate sums (enc ge / dec g1)
  __shared__ float  GB[32];      // dec g2
  __shared__ float  bd[32];      // decoder bias
  __shared__ float  redE[4];     // energy (eh part)
  __shared__ float  redE2[4];    // energy (dh part)
  __shared__ float  red[8];      // softmax sums (8 waves)
  __shared__ float  red2[4];     // out-dot reduce
  __shared__ int    sbad;

  const int b    = blockIdx.x;
  const int tid  = threadIdx.x;
  const int w    = tid >> 6;
  const int lane = tid & 63;
  const int ri   = lane & 3;    // row-in-wave
  const int s16  = lane >> 2;   // K-segment 0..15 (64 floats)
  const int g    = w >> 1;      // gate index
  const int j    = ((w & 1) << 2) + ri;  // h-row within block's 8

  if (b < ENC_BLK) {
    // =========================== encoder group ===============================
    const int e = b;
    const int r = (g << 10) + (e << 3) + j;  // owned gate row
    const int rotE = (e * 37) & 127;         // sentinel->producer spread
    float4 we[16];
#pragma unroll
    for (int k = 0; k < 16; k++) {
      const int m = (k + s16) & 15;
      we[k] = *(const float4*)&Whhe[(size_t)r * 1024 + s16 * 64 + m * 4];
    }
    if (tid < 256) xbuf[tid] = make_float4(0.f, 0.f, 0.f, 0.f);
    if (tid == 0) sbad = 0;
    float ec = 0.f;  // cell state (tid<8)
    __syncthreads();

    for (int t = 0; t < T_STEPS; t++) {
      float ge = 0.f;
#pragma unroll
      for (int k = 0; k < 16; k++) {
        const int m = (k + s16) & 15;
        const float4 x = xbuf[s16 * 16 + m];
        ge += we[k].x * x.x + we[k].y * x.y + we[k].z * x.z + we[k].w * x.w;
      }
      if (s16 == 0) ge += px[((size_t)t * 1024 + (e << 3) + j) * 4 + g];
      ge += __shfl_xor(ge, 4, 64);
      ge += __shfl_xor(ge, 8, 64);
      ge += __shfl_xor(ge, 16, 64);
      ge += __shfl_xor(ge, 32, 64);
      if (lane < 4) GA[w * 4 + lane] = ge;  // GA[g*8+j]
      __syncthreads();  // S1
      if (tid < 8) {
        const float gi = GA[tid], gf = GA[8 + tid], gg = GA[16 + tid], go = GA[24 + tid];
        const float c = sigf(gf) * ec + sigf(gi) * tanhf(gg);
        ec = c;
        const float h = sigf(go) * tanhf(c);
        st_bypass4(&ehbuf[(size_t)t * 1024 + (e << 3) + tid], h);  // coalesced 32B
      }
      // sentinels: waves 6-7 watch one granule per producer (throttled poll)
      if (tid >= 384) {
        int oks;
        const int p = ((tid - 384) + rotE) & 127;
        (void)poll2<2>(&ehbuf[(size_t)t * 1024 + p * 8], &oks);
      }
      __syncthreads();  // Sg: sampled producers visible -> frontier ~complete
      int ok = 1;
      if (tid < 256) {
        fv4 ev = ld_once4(&ehbuf[(size_t)t * 1024 + tid * 4]);
        if (!valid4(ev)) ev = poll2<0>(&ehbuf[(size_t)t * 1024 + tid * 4], &ok);
        xbuf[tid] = make_float4(ev.x, ev.y, ev.z, ev.w);
      }
      if (!ok) sbad = 1;
      __syncthreads();  // S2
      if (sbad) break;
    }
  } else {
    // =========================== decoder group ===============================
    const int d = b - ENC_BLK;
    const int r = (g << 10) + (d << 3) + j;  // owned gate row
    const int rotD = (d * 37 + 11) & 127;    // sentinel->producer spread
    float4 w1[16], wr[16];
#pragma unroll
    for (int k = 0; k < 16; k++) {
      const int m = (k + s16) & 15;
      w1[k] = *(const float4*)&Wihd[(size_t)r * 2048 + s16 * 64 + m * 4];
      const float4 a = *(const float4*)&Wihd[(size_t)r * 2048 + 1024 + s16 * 64 + m * 4];
      const float4 c = *(const float4*)&Whhd[(size_t)r * 1024 + s16 * 64 + m * 4];
      wr[k] = make_float4(a.x + c.x, a.y + c.y, a.z + c.z, a.w + c.w);
    }
    if (tid < 32) {
      const int gg2 = tid >> 3, jj2 = tid & 7;
      bd[tid] = bihd[(gg2 << 10) + (d << 3) + jj2] + bhhd[(gg2 << 10) + (d << 3) + jj2];
    }
    aw[tid] = 0.f;
    if (tid < 256) {
      xbuf[tid] = make_float4(0.f, 0.f, 0.f, 0.f);
      dbuf[tid] = make_float4(0.f, 0.f, 0.f, 0.f);
    }
    if (tid == 0) sbad = 0;
    float dc = 0.f;  // cell state (tid<8)
    float4 wo = make_float4(0.f, 0.f, 0.f, 0.f);
    if (tid < 256) wo = *(const float4*)&Wout[tid * 4];
    const float boutv = bout[0];
    __syncthreads();

    // loop-carried eh(t) speculative sample (enc runs ahead -> these hit).
    float es0 = 0.f, es1 = 0.f, es2 = 0.f, es3 = 0.f;
    if (tid < 256) {
      const float* pe = &ehbuf[(size_t)tid * 4];
      es0 = ld_f(pe + 0); es1 = ld_f(pe + 1); es2 = ld_f(pe + 2); es3 = ld_f(pe + 3);
    }

    bool failed = false;
    for (int t = 0; t < T_STEPS; t++) {
      // --- softmax partials over stale aw (overlaps in-flight eh samples) ---
      const float battn_t = battn[t];
      const float ex0 = expf(aw[tid]);  // aw in [0,1]: exp safe, no max needed
      float so = (tid == t) ? 0.f : ex0;
#pragma unroll
      for (int mk = 1; mk <= 32; mk <<= 1) so += __shfl_xor(so, mk, 64);
      if (lane == 0) red[w] = so;

      // --- consume eh(t): samples issued last iteration; wait mostly hidden ---
      float4 wae = make_float4(0.f, 0.f, 0.f, 0.f);
      float4 wad = make_float4(0.f, 0.f, 0.f, 0.f);
      float epe = 0.f;
      int ok1 = 1;
      if (tid < 256) {
        wae = *(const float4*)&Wattn[(size_t)t * 2048 + tid * 4];
        wad = *(const float4*)&Wattn[(size_t)t * 2048 + 1024 + tid * 4];
        fv4 ev;
        if (validf(es0, es1, es2, es3)) {
          ev.x = es0; ev.y = es1; ev.z = es2; ev.w = es3;
        } else {
          ev = poll2<0>(&ehbuf[(size_t)t * 1024 + tid * 4], &ok1);
        }
        epe = wae.x * ev.x + wae.y * ev.y + wae.z * ev.z + wae.w * ev.w;
        xbuf[tid] = make_float4(ev.x, ev.y, ev.z, ev.w);
      }
      if (!ok1) sbad = 1;
#pragma unroll
      for (int mk = 1; mk <= 32; mk <<= 1) epe += __shfl_xor(epe, mk, 64);
      if (lane == 0 && w < 4) redE[w] = epe;
      __syncthreads();  // B1
      if (sbad) { failed = true; break; }

      // --- g1 = W1 @ eh(t) (no dh spec samples: they never hit, only added
      //     read pressure exactly in the dh write-commit window) ---
      float g1 = 0.f;
#pragma unroll
      for (int k = 0; k < 16; k++) {
        const int m = (k + s16) & 15;
        const float4 x = xbuf[s16 * 16 + m];
        g1 += w1[k].x * x.x + w1[k].y * x.y + w1[k].z * x.z + w1[k].w * x.w;
      }
      g1 += __shfl_xor(g1, 4, 64);
      g1 += __shfl_xor(g1, 8, 64);
      g1 += __shfl_xor(g1, 16, 64);
      g1 += __shfl_xor(g1, 32, 64);
      if (lane < 4) GA[w * 4 + lane] = g1;

      // --- sentinels: waves 6-7 (idle during consume) discover dh(t-1) ---
      if (t > 0 && tid >= 384) {
        int oks;
        const int p = ((tid - 384) + rotD) & 127;
        (void)poll2<2>(&dhbuf[(size_t)(t - 1) * 1024 + p * 8], &oks);
      }
      __syncthreads();  // Sg: dh frontier ~complete

      // --- consume dh(t-1): one-shot + poison backbone + poll2 backstop ---
      float epd = 0.f;
      int ok2 = 1;
      if (t > 0 && tid < 256) {
        fv4 dv = ld_once4(&dhbuf[(size_t)(t - 1) * 1024 + tid * 4]);
        if (!valid4(dv)) dv = poll2<0>(&dhbuf[(size_t)(t - 1) * 1024 + tid * 4], &ok2);
        epd = wad.x * dv.x + wad.y * dv.y + wad.z * dv.z + wad.w * dv.w;
        dbuf[tid] = make_float4(dv.x, dv.y, dv.z, dv.w);
      }
      if (!ok2) sbad = 1;
#pragma unroll
      for (int mk = 1; mk <= 32; mk <<= 1) epd += __shfl_xor(epd, mk, 64);
      if (lane == 0 && w < 4) redE2[w] = epd;
      __syncthreads();  // B2
      if (sbad) { failed = true; break; }

      // --- g2 = (Wihd[:,H:]+Whhd) @ dh(t-1) ---
      float g2 = 0.f;
#pragma unroll
      for (int k = 0; k < 16; k++) {
        const int m = (k + s16) & 15;
        const float4 dd = dbuf[s16 * 16 + m];
        g2 += wr[k].x * dd.x + wr[k].y * dd.y + wr[k].z * dd.z + wr[k].w * dd.w;
      }
      g2 += __shfl_xor(g2, 4, 64);
      g2 += __shfl_xor(g2, 8, 64);
      g2 += __shfl_xor(g2, 16, 64);
      g2 += __shfl_xor(g2, 32, 64);
      if (lane < 4) GB[w * 4 + lane] = g2;

      // --- softmax finish (all threads redundantly) + aw update ---
      const float e_t = redE[0] + redE[1] + redE[2] + redE[3] +
                        redE2[0] + redE2[1] + redE2[2] + redE2[3] + battn_t;
      const float exden = expf(e_t);
      const float inv = 1.f / (red[0] + red[1] + red[2] + red[3] +
                               red[4] + red[5] + red[6] + red[7] + exden);
      const float awt = exden * inv;
      aw[tid] = ((tid == t) ? exden : ex0) * inv;
      __syncthreads();  // S3 (GA/GB ready)

      // --- decoder cell (tid<8) + coalesced publication ---
      if (tid < 8) {
        const float gi = awt * GA[tid]      + GB[tid]      + bd[tid];
        const float gf = awt * GA[8 + tid]  + GB[8 + tid]  + bd[8 + tid];
        const float gg = awt * GA[16 + tid] + GB[16 + tid] + bd[16 + tid];
        const float go = awt * GA[24 + tid] + GB[24 + tid] + bd[24 + tid];
        const float c = sigf(gf) * dc + sigf(gi) * tanhf(gg);
        dc = c;
        const float h = sigf(go) * tanhf(c);
        st_bypass4(&dhbuf[(size_t)t * 1024 + (d << 3) + tid], h);
      }

      // --- issue eh(t+1) speculative samples (in flight across back edge) ---
      if (tid < 256) {
        const int tn = (t + 1 < T_STEPS) ? (t + 1) : t;  // last iter: harmless
        const float* pe = &ehbuf[(size_t)tn * 1024 + tid * 4];
        es0 = ld_f(pe + 0); es1 = ld_f(pe + 1); es2 = ld_f(pe + 2); es3 = ld_f(pe + 3);
      }
    }

    // --- epilogue: out[t] = W_out·dh(t) + b_out, 4 t-values per block ---
    if (!failed) {
#pragma unroll
      for (int i = 0; i < 4; i++) {
        const int t = d * 4 + i;
        float op = 0.f;
        int ok = 1;
        if (tid < 256) {
          const fv4 dv = poll2<0>(&dhbuf[(size_t)t * 1024 + tid * 4], &ok);
          op = wo.x * dv.x + wo.y * dv.y + wo.z * dv.z + wo.w * dv.w;
        }
        if (!ok) break;
#pragma unroll
        for (int mk = 1; mk <= 32; mk <<= 1) op += __shfl_xor(op, mk, 64);
        if (lane == 0 && w < 4) red2[w] = op;
        __syncthreads();
        if (tid == 0) out[t] = red2[0] + red2[1] + red2[2] + red2[3] + boutv;
        __syncthreads();
      }
    }
  }
}

// ---------------------------------- launch ------------------------------------
extern "C" void kernel_launch(void* const* d_in, const int* in_sizes, int n_in,
                              void* d_out, int out_size, void* d_ws, size_t ws_size,
                              hipStream_t stream) {
  const float* X     = (const float*)d_in[0];
  const float* Wihe  = (const float*)d_in[2];
  const float* Whhe  = (const float*)d_in[3];
  const float* bihe  = (const float*)d_in[4];
  const float* bhhe  = (const float*)d_in[5];
  const float* Wattn = (const float*)d_in[6];
  const float* battn = (const float*)d_in[7];
  const float* Wihd  = (const float*)d_in[8];
  const float* Whhd  = (const float*)d_in[9];
  const float* bihd  = (const float*)d_in[10];
  const float* bhhd  = (const float*)d_in[11];
  const float* Wo    = (const float*)d_in[12];
  const float* bo    = (const float*)d_in[13];
  float* out = (float*)d_out;

  float* ws    = (float*)d_ws;
  float* px    = ws;                                  // 512*1024*4 floats (8 MB)
  float* ehbuf = px + (size_t)T_STEPS * 1024 * 4;     // 512*1024 (2 MB)
  float* dhbuf = ehbuf + (size_t)T_STEPS * 1024;      // 512*1024 (2 MB)
  const size_t need = ((size_t)T_STEPS * 1024 * 6) * sizeof(float);
  if (ws_size < need) return;

  prep_gemm<<<dim3(64, 8), 256, 0, stream>>>(X, Wihe, bihe, bhhe, px);
  lstm_persist<<<NBLK, NTHR, 0, stream>>>(
      Whhe, Wattn, battn, Wihd, Whhd, bihd, bhhd, Wo, bo, px, ehbuf, dhbuf, out);
}

// Round 7
// 1805.680 us; speedup vs baseline: 1.1796x; 1.1382x over previous
//
#include <hip/hip_runtime.h>
#include <math.h>

// TransformersLSTM: T=512, I=512, H=1024, L=512, O=1.
// Split-grid persistent kernel: blocks 0..127 encoder, 128..255 decoder.
// R19 = R12 (best structure, ~1700us steady) + DEVICE-SCOPE (sc1-only) POLLS.
// Evidence chain: R13/R18 killed congestion (sentinel discovery still ~2.6us
// with 500x fewer pollers); R15 killed the store side (device-scope atomic
// publication neutral); R16/R17 killed serialized discovery. The one variable
// never varied: poll-load SCOPE. On gfx94x/gfx950 {sc1,sc0} is a scope field:
// sc0+sc1 = SYSTEM (host-coherent slow path), sc1 alone = DEVICE scope. All
// prior rounds polled at SYSTEM scope. The compiler's AGENT-scope ld_f spec
// samples (device scope) demonstrably observe our sc0sc1 stores (R12 lag
// regime was correct), so device-scope loads are coherent with the data plane.
// Change: phase-1 poll = 2-deep pipelined sc1-only loads, bounded (64 iters);
// timeout -> proven sc0sc1 poll2; per-thread streak disables phase-1 after 2
// consecutive timeouts (bounds the loss if sc1-polling misbehaves). Poison
// backbone unchanged -> soundness identical to R12. Stores stay sc0sc1.

#define T_STEPS 512
#define ENC_BLK 128
#define NBLK    256
#define NTHR    512
#define POLL_LIMIT 30000u
#define FAST_ITERS 64

typedef float fv4 __attribute__((ext_vector_type(4)));

__device__ __forceinline__ float sigf(float x) { return 1.0f / (1.0f + expf(-x)); }

// relaxed agent-scope load: device-coherent dword load, compiler-scheduled.
__device__ __forceinline__ float ld_f(const float* p) {
  return __hip_atomic_load(p, __ATOMIC_RELAXED, __HIP_MEMORY_SCOPE_AGENT);
}

// 4B cache-bypass store (system scope; proven visible to device-scope loads).
__device__ __forceinline__ void st_bypass4(float* p, float v) {
  asm volatile("global_store_dword %0, %1, off sc0 sc1"
               :: "v"(p), "v"(v) : "memory");
}

__device__ __forceinline__ bool valid4(fv4 v) {
  return __float_as_uint(v.x) != 0xAAAAAAAAu && __float_as_uint(v.y) != 0xAAAAAAAAu &&
         __float_as_uint(v.z) != 0xAAAAAAAAu && __float_as_uint(v.w) != 0xAAAAAAAAu;
}
__device__ __forceinline__ bool validf(float a, float b, float c, float d) {
  return __float_as_uint(a) != 0xAAAAAAAAu && __float_as_uint(b) != 0xAAAAAAAAu &&
         __float_as_uint(c) != 0xAAAAAAAAu && __float_as_uint(d) != 0xAAAAAAAAu;
}

// 2-deep pipelined poison-poll, SYSTEM scope (proven backbone / fallback).
__device__ __forceinline__ fv4 poll2(const float* p, int* okp) {
  fv4 a, b;
  int ok = 1;
  asm volatile("global_load_dwordx4 %0, %1, off sc0 sc1" : "=v"(a) : "v"(p) : "memory");
  for (unsigned it = 0;; ++it) {
    asm volatile("global_load_dwordx4 %0, %1, off sc0 sc1" : "=v"(b) : "v"(p) : "memory");
    asm volatile("s_waitcnt vmcnt(1)" : "+v"(a) :: "memory");  // oldest (a) done
    if (valid4(a)) { asm volatile("s_waitcnt vmcnt(0)" ::: "memory"); break; }
    asm volatile("global_load_dwordx4 %0, %1, off sc0 sc1" : "=v"(a) : "v"(p) : "memory");
    asm volatile("s_waitcnt vmcnt(1)" : "+v"(b) :: "memory");  // oldest (b) done
    if (valid4(b)) { asm volatile("s_waitcnt vmcnt(0)" ::: "memory"); a = b; break; }
    if (it > POLL_LIMIT) { ok = 0; asm volatile("s_waitcnt vmcnt(0)" ::: "memory"); break; }
  }
  *okp = ok;
  return a;
}

// Hybrid poll: phase-1 DEVICE-scope (sc1-only) 2-deep pipelined, bounded;
// phase-2 proven system-scope poll2. strk = consecutive phase-1 timeouts;
// phase-1 self-disables after 2 (bounds loss if sc1 polling misbehaves).
__device__ __forceinline__ fv4 poll2h(const float* p, int* okp, int* strk) {
  fv4 a, b;
  if (*strk < 2) {
    asm volatile("global_load_dwordx4 %0, %1, off sc1" : "=v"(a) : "v"(p) : "memory");
    for (int it = 0; it < FAST_ITERS; ++it) {
      asm volatile("global_load_dwordx4 %0, %1, off sc1" : "=v"(b) : "v"(p) : "memory");
      asm volatile("s_waitcnt vmcnt(1)" : "+v"(a) :: "memory");
      if (valid4(a)) { asm volatile("s_waitcnt vmcnt(0)" ::: "memory"); *strk = 0; *okp = 1; return a; }
      asm volatile("global_load_dwordx4 %0, %1, off sc1" : "=v"(a) : "v"(p) : "memory");
      asm volatile("s_waitcnt vmcnt(1)" : "+v"(b) :: "memory");
      if (valid4(b)) { asm volatile("s_waitcnt vmcnt(0)" ::: "memory"); *strk = 0; *okp = 1; return b; }
    }
    asm volatile("s_waitcnt vmcnt(0)" ::: "memory");
    (*strk)++;
  }
  return poll2(p, okp);
}

// ------------- precompute PX = W_ih_e @ x_t + b_ih_e + b_hh_e -----------------
// px[(t*1024 + h)*4 + g] for gate row r = g*1024 + h.
__global__ __launch_bounds__(256) void prep_gemm(const float* __restrict__ X,
                                                 const float* __restrict__ Wih,
                                                 const float* __restrict__ bih,
                                                 const float* __restrict__ bhh,
                                                 float* __restrict__ px) {
  __shared__ float Ws[64][68];
  __shared__ float Xs[64][68];
  const int r0 = blockIdx.x * 64;
  const int t0 = blockIdx.y * 64;
  const int tid = threadIdx.x;
  const int tr = tid & 15;
  const int tc = tid >> 4;
  float acc[4][4] = {{0.f}};
  for (int k0 = 0; k0 < 512; k0 += 64) {
    __syncthreads();
    const int lr = tid >> 4;
    const int lc = (tid & 15) * 4;
#pragma unroll
    for (int rep = 0; rep < 4; rep++) {
      const int row = lr + rep * 16;
      const float4 wv = *(const float4*)&Wih[(size_t)(r0 + row) * 512 + k0 + lc];
      Ws[lc + 0][row] = wv.x; Ws[lc + 1][row] = wv.y;
      Ws[lc + 2][row] = wv.z; Ws[lc + 3][row] = wv.w;
      const float4 xv = *(const float4*)&X[(size_t)(t0 + row) * 512 + k0 + lc];
      Xs[row][lc + 0] = xv.x; Xs[row][lc + 1] = xv.y;
      Xs[row][lc + 2] = xv.z; Xs[row][lc + 3] = xv.w;
    }
    __syncthreads();
    for (int kk = 0; kk < 64; kk++) {
      float a[4], x[4];
#pragma unroll
      for (int i = 0; i < 4; i++) a[i] = Ws[kk][tr * 4 + i];
#pragma unroll
      for (int j = 0; j < 4; j++) x[j] = Xs[tc * 4 + j][kk];
#pragma unroll
      for (int i = 0; i < 4; i++)
#pragma unroll
        for (int j = 0; j < 4; j++) acc[i][j] += a[i] * x[j];
    }
  }
#pragma unroll
  for (int i = 0; i < 4; i++) {
    const int r = r0 + tr * 4 + i;
    const int g = r >> 10, h = r & 1023;
    const float bsum = bih[r] + bhh[r];
#pragma unroll
    for (int j = 0; j < 4; j++) {
      const int t = t0 + tc * 4 + j;
      px[((size_t)t * 1024 + h) * 4 + g] = acc[i][j] + bsum;
    }
  }
}

// ------------------------------ persistent kernel -----------------------------
// 512 threads: wave w (0..7) owns gate g=w>>1, h-rows j=(w&1)*4+ri (ri=lane&3);
// lane s16=lane>>2 covers K in [s16*64, s16*64+64) as 16 float4 (rot by s16).
__global__ __launch_bounds__(512, 1) void lstm_persist(
    const float* __restrict__ Whhe, const float* __restrict__ Wattn,
    const float* __restrict__ battn, const float* __restrict__ Wihd,
    const float* __restrict__ Whhd, const float* __restrict__ bihd,
    const float* __restrict__ bhhd, const float* __restrict__ Wout,
    const float* __restrict__ bout, const float* __restrict__ px,
    float* ehbuf, float* dhbuf, float* out) {
  __shared__ float4 xbuf[256];   // eh copy (both groups)
  __shared__ float4 dbuf[256];   // dh copy (decoder)
  __shared__ float  aw[512];     // softmax state (decoder)
  __shared__ float  GA[32];      // gate sums (enc ge / dec g1)
  __shared__ float  GB[32];      // dec g2
  __shared__ float  bd[32];      // decoder bias
  __shared__ float  redE[4];     // energy (eh part)
  __shared__ float  redE2[4];    // energy (dh part)
  __shared__ float  red[8];      // softmax sums (8 waves)
  __shared__ float  red2[4];     // out-dot reduce
  __shared__ int    sbad;

  const int b    = blockIdx.x;
  const int tid  = threadIdx.x;
  const int w    = tid >> 6;
  const int lane = tid & 63;
  const int ri   = lane & 3;    // row-in-wave
  const int s16  = lane >> 2;   // K-segment 0..15 (64 floats)
  const int g    = w >> 1;      // gate index
  const int j    = ((w & 1) << 2) + ri;  // h-row within block's 8

  if (b < ENC_BLK) {
    // =========================== encoder group ===============================
    const int e = b;
    const int r = (g << 10) + (e << 3) + j;  // owned gate row
    float4 we[16];
#pragma unroll
    for (int k = 0; k < 16; k++) {
      const int m = (k + s16) & 15;
      we[k] = *(const float4*)&Whhe[(size_t)r * 1024 + s16 * 64 + m * 4];
    }
    if (tid < 256) xbuf[tid] = make_float4(0.f, 0.f, 0.f, 0.f);
    if (tid == 0) sbad = 0;
    float ec = 0.f;  // cell state (tid<8)
    int strkE = 0;   // phase-1 health (per-thread)
    __syncthreads();

    for (int t = 0; t < T_STEPS; t++) {
      float ge = 0.f;
#pragma unroll
      for (int k = 0; k < 16; k++) {
        const int m = (k + s16) & 15;
        const float4 x = xbuf[s16 * 16 + m];
        ge += we[k].x * x.x + we[k].y * x.y + we[k].z * x.z + we[k].w * x.w;
      }
      if (s16 == 0) ge += px[((size_t)t * 1024 + (e << 3) + j) * 4 + g];
      ge += __shfl_xor(ge, 4, 64);
      ge += __shfl_xor(ge, 8, 64);
      ge += __shfl_xor(ge, 16, 64);
      ge += __shfl_xor(ge, 32, 64);
      if (lane < 4) GA[w * 4 + lane] = ge;  // GA[g*8+j]
      __syncthreads();  // S1
      if (tid < 8) {
        const float gi = GA[tid], gf = GA[8 + tid], gg = GA[16 + tid], go = GA[24 + tid];
        const float c = sigf(gf) * ec + sigf(gi) * tanhf(gg);
        ec = c;
        const float h = sigf(go) * tanhf(c);
        st_bypass4(&ehbuf[(size_t)t * 1024 + (e << 3) + tid], h);  // coalesced 32B
      }
      int ok = 1;
      if (tid < 256) {
        const fv4 ev = poll2h(&ehbuf[(size_t)t * 1024 + tid * 4], &ok, &strkE);
        xbuf[tid] = make_float4(ev.x, ev.y, ev.z, ev.w);
      }
      if (!ok) sbad = 1;
      __syncthreads();  // S2
      if (sbad) break;
    }
  } else {
    // =========================== decoder group ===============================
    const int d = b - ENC_BLK;
    const int r = (g << 10) + (d << 3) + j;  // owned gate row
    float4 w1[16], wr[16];
#pragma unroll
    for (int k = 0; k < 16; k++) {
      const int m = (k + s16) & 15;
      w1[k] = *(const float4*)&Wihd[(size_t)r * 2048 + s16 * 64 + m * 4];
      const float4 a = *(const float4*)&Wihd[(size_t)r * 2048 + 1024 + s16 * 64 + m * 4];
      const float4 c = *(const float4*)&Whhd[(size_t)r * 1024 + s16 * 64 + m * 4];
      wr[k] = make_float4(a.x + c.x, a.y + c.y, a.z + c.z, a.w + c.w);
    }
    if (tid < 32) {
      const int gg2 = tid >> 3, jj2 = tid & 7;
      bd[tid] = bihd[(gg2 << 10) + (d << 3) + jj2] + bhhd[(gg2 << 10) + (d << 3) + jj2];
    }
    aw[tid] = 0.f;
    if (tid < 256) {
      xbuf[tid] = make_float4(0.f, 0.f, 0.f, 0.f);
      dbuf[tid] = make_float4(0.f, 0.f, 0.f, 0.f);
    }
    if (tid == 0) sbad = 0;
    float dc = 0.f;  // cell state (tid<8)
    int strkE2 = 0, strkD = 0;  // phase-1 health (per-thread)
    float4 wo = make_float4(0.f, 0.f, 0.f, 0.f);
    if (tid < 256) wo = *(const float4*)&Wout[tid * 4];
    const float boutv = bout[0];
    __syncthreads();

    // loop-carried eh(t) speculative sample (compiler-managed in-flight).
    float es0 = 0.f, es1 = 0.f, es2 = 0.f, es3 = 0.f;
    if (tid < 256) {
      const float* pe = &ehbuf[(size_t)tid * 4];
      es0 = ld_f(pe + 0); es1 = ld_f(pe + 1); es2 = ld_f(pe + 2); es3 = ld_f(pe + 3);
    }

    bool failed = false;
    for (int t = 0; t < T_STEPS; t++) {
      // --- softmax partials over stale aw (overlaps in-flight eh samples) ---
      const float battn_t = battn[t];
      const float ex0 = expf(aw[tid]);  // aw in [0,1]: exp safe, no max needed
      float so = (tid == t) ? 0.f : ex0;
#pragma unroll
      for (int mk = 1; mk <= 32; mk <<= 1) so += __shfl_xor(so, mk, 64);
      if (lane == 0) red[w] = so;

      // --- consume eh(t): samples issued last iteration; wait mostly hidden ---
      float4 wae = make_float4(0.f, 0.f, 0.f, 0.f);
      float4 wad = make_float4(0.f, 0.f, 0.f, 0.f);
      float epe = 0.f;
      int ok1 = 1;
      if (tid < 256) {
        wae = *(const float4*)&Wattn[(size_t)t * 2048 + tid * 4];
        wad = *(const float4*)&Wattn[(size_t)t * 2048 + 1024 + tid * 4];
        fv4 ev;
        if (validf(es0, es1, es2, es3)) {
          ev.x = es0; ev.y = es1; ev.z = es2; ev.w = es3;
        } else {
          ev = poll2h(&ehbuf[(size_t)t * 1024 + tid * 4], &ok1, &strkE2);
        }
        epe = wae.x * ev.x + wae.y * ev.y + wae.z * ev.z + wae.w * ev.w;
        xbuf[tid] = make_float4(ev.x, ev.y, ev.z, ev.w);
      }
      if (!ok1) sbad = 1;
#pragma unroll
      for (int mk = 1; mk <= 32; mk <<= 1) epe += __shfl_xor(epe, mk, 64);
      if (lane == 0 && w < 4) redE[w] = epe;
      __syncthreads();  // B1
      if (sbad) { failed = true; break; }

      // --- issue dh(t-1) speculative samples; g1 matvec covers the RTT ---
      float ds0 = 0.f, ds1 = 0.f, ds2 = 0.f, ds3 = 0.f;
      if (t > 0 && tid < 256) {
        const float* pd = &dhbuf[(size_t)(t - 1) * 1024 + tid * 4];
        ds0 = ld_f(pd + 0); ds1 = ld_f(pd + 1); ds2 = ld_f(pd + 2); ds3 = ld_f(pd + 3);
      }

      float g1 = 0.f;
#pragma unroll
      for (int k = 0; k < 16; k++) {
        const int m = (k + s16) & 15;
        const float4 x = xbuf[s16 * 16 + m];
        g1 += w1[k].x * x.x + w1[k].y * x.y + w1[k].z * x.z + w1[k].w * x.w;
      }
      g1 += __shfl_xor(g1, 4, 64);
      g1 += __shfl_xor(g1, 8, 64);
      g1 += __shfl_xor(g1, 16, 64);
      g1 += __shfl_xor(g1, 32, 64);
      if (lane < 4) GA[w * 4 + lane] = g1;

      // --- consume dh(t-1): the recurrence-critical wait ---
      float epd = 0.f;
      int ok2 = 1;
      if (t > 0 && tid < 256) {
        fv4 dv;
        if (validf(ds0, ds1, ds2, ds3)) {
          dv.x = ds0; dv.y = ds1; dv.z = ds2; dv.w = ds3;
        } else {
          dv = poll2h(&dhbuf[(size_t)(t - 1) * 1024 + tid * 4], &ok2, &strkD);
        }
        epd = wad.x * dv.x + wad.y * dv.y + wad.z * dv.z + wad.w * dv.w;
        dbuf[tid] = make_float4(dv.x, dv.y, dv.z, dv.w);
      }
      if (!ok2) sbad = 1;
#pragma unroll
      for (int mk = 1; mk <= 32; mk <<= 1) epd += __shfl_xor(epd, mk, 64);
      if (lane == 0 && w < 4) redE2[w] = epd;
      __syncthreads();  // B2
      if (sbad) { failed = true; break; }

      // --- g2 = (Wihd[:,H:]+Whhd) @ dh(t-1) ---
      float g2 = 0.f;
#pragma unroll
      for (int k = 0; k < 16; k++) {
        const int m = (k + s16) & 15;
        const float4 dd = dbuf[s16 * 16 + m];
        g2 += wr[k].x * dd.x + wr[k].y * dd.y + wr[k].z * dd.z + wr[k].w * dd.w;
      }
      g2 += __shfl_xor(g2, 4, 64);
      g2 += __shfl_xor(g2, 8, 64);
      g2 += __shfl_xor(g2, 16, 64);
      g2 += __shfl_xor(g2, 32, 64);
      if (lane < 4) GB[w * 4 + lane] = g2;

      // --- softmax finish (all threads redundantly) + aw update ---
      const float e_t = redE[0] + redE[1] + redE[2] + redE[3] +
                        redE2[0] + redE2[1] + redE2[2] + redE2[3] + battn_t;
      const float exden = expf(e_t);
      const float inv = 1.f / (red[0] + red[1] + red[2] + red[3] +
                               red[4] + red[5] + red[6] + red[7] + exden);
      const float awt = exden * inv;
      aw[tid] = ((tid == t) ? exden : ex0) * inv;
      __syncthreads();  // S3 (GA/GB ready)

      // --- decoder cell (tid<8) + coalesced publication ---
      if (tid < 8) {
        const float gi = awt * GA[tid]      + GB[tid]      + bd[tid];
        const float gf = awt * GA[8 + tid]  + GB[8 + tid]  + bd[8 + tid];
        const float gg = awt * GA[16 + tid] + GB[16 + tid] + bd[16 + tid];
        const float go = awt * GA[24 + tid] + GB[24 + tid] + bd[24 + tid];
        const float c = sigf(gf) * dc + sigf(gi) * tanhf(gg);
        dc = c;
        const float h = sigf(go) * tanhf(c);
        st_bypass4(&dhbuf[(size_t)t * 1024 + (d << 3) + tid], h);
      }

      // --- issue eh(t+1) speculative samples (in flight across back edge) ---
      if (tid < 256) {
        const int tn = (t + 1 < T_STEPS) ? (t + 1) : t;  // last iter: harmless
        const float* pe = &ehbuf[(size_t)tn * 1024 + tid * 4];
        es0 = ld_f(pe + 0); es1 = ld_f(pe + 1); es2 = ld_f(pe + 2); es3 = ld_f(pe + 3);
      }
    }

    // --- epilogue: out[t] = W_out·dh(t) + b_out, 4 t-values per block ---
    if (!failed) {
#pragma unroll
      for (int i = 0; i < 4; i++) {
        const int t = d * 4 + i;
        float op = 0.f;
        int ok = 1;
        if (tid < 256) {
          const fv4 dv = poll2(&dhbuf[(size_t)t * 1024 + tid * 4], &ok);
          op = wo.x * dv.x + wo.y * dv.y + wo.z * dv.z + wo.w * dv.w;
        }
        if (!ok) break;
#pragma unroll
        for (int mk = 1; mk <= 32; mk <<= 1) op += __shfl_xor(op, mk, 64);
        if (lane == 0 && w < 4) red2[w] = op;
        __syncthreads();
        if (tid == 0) out[t] = red2[0] + red2[1] + red2[2] + red2[3] + boutv;
        __syncthreads();
      }
    }
  }
}

// ---------------------------------- launch ------------------------------------
extern "C" void kernel_launch(void* const* d_in, const int* in_sizes, int n_in,
                              void* d_out, int out_size, void* d_ws, size_t ws_size,
                              hipStream_t stream) {
  const float* X     = (const float*)d_in[0];
  const float* Wihe  = (const float*)d_in[2];
  const float* Whhe  = (const float*)d_in[3];
  const float* bihe  = (const float*)d_in[4];
  const float* bhhe  = (const float*)d_in[5];
  const float* Wattn = (const float*)d_in[6];
  const float* battn = (const float*)d_in[7];
  const float* Wihd  = (const float*)d_in[8];
  const float* Whhd  = (const float*)d_in[9];
  const float* bihd  = (const float*)d_in[10];
  const float* bhhd  = (const float*)d_in[11];
  const float* Wo    = (const float*)d_in[12];
  const float* bo    = (const float*)d_in[13];
  float* out = (float*)d_out;

  float* ws    = (float*)d_ws;
  float* px    = ws;                                  // 512*1024*4 floats (8 MB)
  float* ehbuf = px + (size_t)T_STEPS * 1024 * 4;     // 512*1024 (2 MB)
  float* dhbuf = ehbuf + (size_t)T_STEPS * 1024;      // 512*1024 (2 MB)
  const size_t need = ((size_t)T_STEPS * 1024 * 6) * sizeof(float);
  if (ws_size < need) return;

  prep_gemm<<<dim3(64, 8), 256, 0, stream>>>(X, Wihe, bihe, bhhe, px);
  lstm_persist<<<NBLK, NTHR, 0, stream>>>(
      Whhe, Wattn, battn, Wihd, Whhd, bihd, bhhd, Wo, bo, px, ehbuf, dhbuf, out);
}